// Round 5
// baseline (502.106 us; speedup 1.0000x reference)
//
#include <hip/hip_runtime.h>
#include <hip/hip_bf16.h>
#include <stdint.h>

#define V 32000
#define E 256
#define H 256
#define KCTX 3
#define S 2048
#define B 4
#define M (S * B)      // 8192 rows
#define K1 (KCTX * E)  // 768

typedef __attribute__((ext_vector_type(8))) short s16x8;
typedef __attribute__((ext_vector_type(4))) short s16x4;
typedef __attribute__((ext_vector_type(4))) float f32x4;

typedef const __attribute__((address_space(1))) unsigned short* gas_t;
typedef __attribute__((address_space(3))) unsigned short* las_t;

static __device__ __forceinline__ unsigned short f2bf(float f) {
  union { float f; unsigned u; } v; v.f = f;
  unsigned u = v.u;
  unsigned r = (u + 0x7fffu + ((u >> 16) & 1u)) >> 16;  // RNE
  return (unsigned short)r;
}

// ---------------------------------------------------------------------------
// Transpose + cast: in (R x C) f32  ->  out (C x R) bf16.  R%32==0, C%32==0.
// ---------------------------------------------------------------------------
__global__ void k_transpose_cast(const float* __restrict__ in,
                                 unsigned short* __restrict__ out,
                                 int R, int C) {
  __shared__ float tile[32][33];
  int bx = blockIdx.x;               // column-tile
  int by = blockIdx.y;               // row-tile
  int tx = threadIdx.x & 31;
  int ty = threadIdx.x >> 5;         // 0..7
#pragma unroll
  for (int i = 0; i < 32; i += 8)
    tile[ty + i][tx] = in[(size_t)(by * 32 + ty + i) * C + bx * 32 + tx];
  __syncthreads();
#pragma unroll
  for (int i = 0; i < 32; i += 8)
    out[(size_t)(bx * 32 + ty + i) * R + by * 32 + tx] = f2bf(tile[tx][ty + i]);
}

// ---------------------------------------------------------------------------
// Stage 1: h = silu(x @ w1 + b1), h bf16 (8192 x 256).
// Block = 4 waves = one 16-row M-tile; x-tile gathered once into LDS.
// ---------------------------------------------------------------------------
__global__ __launch_bounds__(256) void k_stage1(
    const int* __restrict__ tok, const float* __restrict__ embed,
    const unsigned short* __restrict__ w1T,  // (H x K1) bf16, w1T[n][k]
    const float* __restrict__ b1, unsigned short* __restrict__ hbuf) {
  __shared__ unsigned short xlds[16][K1 + 8];
  __shared__ int toks[48];
  int bid = blockIdx.x;        // 0..511
  int t = threadIdx.x;
  int m0 = bid * 16;

  if (t < 48) {
    int r = t / 3, kk = t - r * 3;
    int m = m0 + r, s = m >> 2, bb = m & 3;
    int tp = s - KCTX + kk;
    toks[t] = (tp >= 0) ? tok[tp * B + bb] : 0;
  }
  __syncthreads();

#pragma unroll
  for (int j = 0; j < 12; j++) {
    int c = j * 256 + t;
    int r = c / 192;           // 192 float4 per x-row
    int cc = c - r * 192;      // 0..191
    int kk = cc >> 6;
    int e4 = cc & 63;
    f32x4 v = *reinterpret_cast<const f32x4*>(
        embed + (size_t)toks[r * 3 + kk] * E + e4 * 4);
    s16x4 o;
#pragma unroll
    for (int jj = 0; jj < 4; jj++) o[jj] = (short)f2bf(v[jj]);
    *reinterpret_cast<s16x4*>(&xlds[r][cc * 4]) = o;
  }
  __syncthreads();

  int l = t & 63;
  int wv = t >> 6;
  int n0 = wv * 64;

  f32x4 zero = {0.f, 0.f, 0.f, 0.f};
  f32x4 acc[4];
#pragma unroll
  for (int ni = 0; ni < 4; ni++) acc[ni] = zero;

#pragma unroll
  for (int kt = 0; kt < 24; kt++) {
    s16x8 a = *reinterpret_cast<const s16x8*>(&xlds[l & 15][kt * 32 + (l >> 4) * 8]);
#pragma unroll
    for (int ni = 0; ni < 4; ni++) {
      int n = n0 + ni * 16 + (l & 15);
      s16x8 bf = *reinterpret_cast<const s16x8*>(
          w1T + (size_t)n * K1 + kt * 32 + (l >> 4) * 8);
      acc[ni] = __builtin_amdgcn_mfma_f32_16x16x32_bf16(a, bf, acc[ni], 0, 0, 0);
    }
  }

  int rbase = m0 + (l >> 4) * 4;
#pragma unroll
  for (int ni = 0; ni < 4; ni++) {
    int n = n0 + ni * 16 + (l & 15);
    float bias = b1[n];
#pragma unroll
    for (int j = 0; j < 4; j++) {
      float vv = acc[ni][j] + bias;
      float sv = vv / (1.0f + __expf(-vv));
      hbuf[(size_t)(rbase + j) * H + n] = f2bf(sv);
    }
  }
}

// ---------------------------------------------------------------------------
// Stage 2: out = h @ w2 + b2  (8192 x 32000, K=256).
// 256x128 tile, 8 waves (4Mx2N, 64x64 per wave), BK=32, double-buffered
// 48 KiB LDS -> 2 blocks/CU (epilogue-write overlap). T3-minimum schedule:
// stage(t+1) issued BEFORE compute(t), one __syncthreads per K-step (full
// fence: race-free by construction). Both-sides XOR swizzle (rule 21):
// chunk ^ ((row>>1)&3) on pre-swizzled global src + on ds_read -> 2-way
// bank alias (free) instead of 16-way conflict.
// Grid 8000 = 8 XCD x 1000, M-fastest -> per-XCD w2T slice L2-resident.
// ---------------------------------------------------------------------------
__global__ __launch_bounds__(512, 4) void k_stage2(
    const unsigned short* __restrict__ hbuf,  // (8192 x 256) bf16
    const unsigned short* __restrict__ w2T,   // (32000 x 256) bf16
    const float* __restrict__ b2, float* __restrict__ out) {
  __shared__ unsigned short lds[2][12288];  // per buf: A 256x32 (8192) + B 128x32 (4096)

  int bid = blockIdx.x;
  int rb = (bid & 7) * 1000 + (bid >> 3);  // bijective: 8000 = 8*1000
  int mtile = rb & 31;                     // 32 M-tiles of 256 (fastest)
  int ntile = rb >> 5;                     // 250 N-tiles of 128
  int m_base = mtile * 256, n_base = ntile * 128;

  int t = threadIdx.x;
  int l = t & 63;
  int wv = t >> 6;                // 0..7
  int wm = wv >> 1, wn = wv & 1;  // 4x2 wave grid; wave computes 64x64

  int srow = l >> 2;   // lane's row within a 16-row staging call (64B rows)
  int c4 = l & 3;      // lane's 16B chunk within a 64B row

  f32x4 zero = {0.f, 0.f, 0.f, 0.f};
  f32x4 acc[4][4];
#pragma unroll
  for (int mi = 0; mi < 4; mi++)
#pragma unroll
    for (int ni = 0; ni < 4; ni++) acc[mi][ni] = zero;

  // stage K-slice tt (BK=32) into buffer p: 3 gload_lds per wave.
  // Global source chunk is XOR-permuted so linear LDS dest leaves data at
  // chunk (c ^ ((row>>1)&3))  [rule 21: swizzle both sides or neither].
  auto stage = [&](int tt, int p) {
    int gk = tt * 32;
#pragma unroll
    for (int j = 0; j < 2; j++) {          // A: 256 rows
      int r0 = wv * 32 + j * 16;
      int row = r0 + srow;
      int gc = c4 ^ ((row >> 1) & 3);
      const unsigned short* ga =
          hbuf + (size_t)(m_base + row) * 256 + gk + gc * 8;
      __builtin_amdgcn_global_load_lds((gas_t)ga, (las_t)&lds[p][r0 * 32], 16, 0, 0);
    }
    {                                      // B: 128 rows
      int r0 = wv * 16;
      int row = r0 + srow;
      int gc = c4 ^ ((row >> 1) & 3);
      const unsigned short* gb =
          w2T + (size_t)(n_base + row) * 256 + gk + gc * 8;
      __builtin_amdgcn_global_load_lds((gas_t)gb, (las_t)&lds[p][8192 + r0 * 32], 16, 0, 0);
    }
  };

  auto compute = [&](int p) {
    const unsigned short* bufA = &lds[p][0];
    const unsigned short* bufB = &lds[p][8192];
    int c = l >> 4;  // lane's K-chunk (0..3)
    s16x8 af[4], bfr[4];
#pragma unroll
    for (int mi = 0; mi < 4; mi++) {
      int row = wm * 64 + mi * 16 + (l & 15);
      af[mi] = *reinterpret_cast<const s16x8*>(
          bufA + row * 32 + (c ^ ((row >> 1) & 3)) * 8);
    }
#pragma unroll
    for (int ni = 0; ni < 4; ni++) {
      int row = wn * 64 + ni * 16 + (l & 15);
      bfr[ni] = *reinterpret_cast<const s16x8*>(
          bufB + row * 32 + (c ^ ((row >> 1) & 3)) * 8);
    }
#pragma unroll
    for (int mi = 0; mi < 4; mi++)
#pragma unroll
      for (int ni = 0; ni < 4; ni++)
        acc[mi][ni] = __builtin_amdgcn_mfma_f32_16x16x32_bf16(
            af[mi], bfr[ni], acc[mi][ni], 0, 0, 0);
  };

  stage(0, 0);
  __syncthreads();
#pragma unroll
  for (int tt = 0; tt < 8; tt++) {
    if (tt < 7) stage(tt + 1, (tt + 1) & 1);  // prefetch: flies during compute
    compute(tt & 1);
    __syncthreads();  // full fence: loads landed + all reads of buf done
  }

  // epilogue: + b2, f32 store
#pragma unroll
  for (int ni = 0; ni < 4; ni++) {
    int col = n_base + wn * 64 + ni * 16 + (l & 15);
    float bias = b2[col];
#pragma unroll
    for (int mi = 0; mi < 4; mi++) {
      int row0 = m_base + wm * 64 + mi * 16 + ((l >> 4) * 4);
#pragma unroll
      for (int j = 0; j < 4; j++)
        out[(size_t)(row0 + j) * V + col] = acc[mi][ni][j] + bias;
    }
  }
}

// ---------------------------------------------------------------------------
extern "C" void kernel_launch(void* const* d_in, const int* in_sizes, int n_in,
                              void* d_out, int out_size, void* d_ws,
                              size_t ws_size, hipStream_t stream) {
  const int* tokens = (const int*)d_in[0];     // (S, B)
  const float* embed = (const float*)d_in[1];  // (V, E)
  const float* w1 = (const float*)d_in[2];     // (K1, H)
  const float* b1 = (const float*)d_in[3];     // (H)
  const float* w2 = (const float*)d_in[4];     // (H, V)
  const float* b2 = (const float*)d_in[5];     // (V)
  float* out = (float*)d_out;

  unsigned short* w2T = (unsigned short*)d_ws;          // V*E   bf16
  unsigned short* w1T = w2T + (size_t)V * E;            // H*K1  bf16
  unsigned short* hb  = w1T + (size_t)H * K1;           // M*H   bf16

  k_transpose_cast<<<dim3(V / 32, H / 32), 256, 0, stream>>>(w2, w2T, H, V);
  k_transpose_cast<<<dim3(H / 32, K1 / 32), 256, 0, stream>>>(w1, w1T, K1, H);
  k_stage1<<<512, 256, 0, stream>>>(tokens, embed, w1T, b1, hb);
  k_stage2<<<8000, 512, 0, stream>>>(hb, w2T, b2, out);
}

// Round 6
// 409.795 us; speedup vs baseline: 1.2253x; 1.2253x over previous
//
#include <hip/hip_runtime.h>
#include <hip/hip_bf16.h>
#include <stdint.h>

#define V 32000
#define E 256
#define H 256
#define KCTX 3
#define S 2048
#define B 4
#define M (S * B)      // 8192 rows
#define K1 (KCTX * E)  // 768

typedef __attribute__((ext_vector_type(8))) short s16x8;
typedef __attribute__((ext_vector_type(4))) short s16x4;
typedef __attribute__((ext_vector_type(4))) float f32x4;

typedef const __attribute__((address_space(1))) unsigned short* gas_t;
typedef __attribute__((address_space(3))) unsigned short* las_t;

static __device__ __forceinline__ unsigned short f2bf(float f) {
  union { float f; unsigned u; } v; v.f = f;
  unsigned u = v.u;
  unsigned r = (u + 0x7fffu + ((u >> 16) & 1u)) >> 16;  // RNE
  return (unsigned short)r;
}

// ---------------------------------------------------------------------------
// Transpose + cast: in (R x C) f32  ->  out (C x R) bf16.  R%32==0, C%32==0.
// ---------------------------------------------------------------------------
__global__ void k_transpose_cast(const float* __restrict__ in,
                                 unsigned short* __restrict__ out,
                                 int R, int C) {
  __shared__ float tile[32][33];
  int bx = blockIdx.x;               // column-tile
  int by = blockIdx.y;               // row-tile
  int tx = threadIdx.x & 31;
  int ty = threadIdx.x >> 5;         // 0..7
#pragma unroll
  for (int i = 0; i < 32; i += 8)
    tile[ty + i][tx] = in[(size_t)(by * 32 + ty + i) * C + bx * 32 + tx];
  __syncthreads();
#pragma unroll
  for (int i = 0; i < 32; i += 8)
    out[(size_t)(bx * 32 + ty + i) * R + by * 32 + tx] = f2bf(tile[tx][ty + i]);
}

// ---------------------------------------------------------------------------
// Stage 1: h = silu(x @ w1 + b1), h bf16 (8192 x 256).
// Block = 4 waves = one 16-row M-tile; x-tile gathered once into LDS.
// ---------------------------------------------------------------------------
__global__ __launch_bounds__(256) void k_stage1(
    const int* __restrict__ tok, const float* __restrict__ embed,
    const unsigned short* __restrict__ w1T,  // (H x K1) bf16, w1T[n][k]
    const float* __restrict__ b1, unsigned short* __restrict__ hbuf) {
  __shared__ unsigned short xlds[16][K1 + 8];
  __shared__ int toks[48];
  int bid = blockIdx.x;        // 0..511
  int t = threadIdx.x;
  int m0 = bid * 16;

  if (t < 48) {
    int r = t / 3, kk = t - r * 3;
    int m = m0 + r, s = m >> 2, bb = m & 3;
    int tp = s - KCTX + kk;
    toks[t] = (tp >= 0) ? tok[tp * B + bb] : 0;
  }
  __syncthreads();

#pragma unroll
  for (int j = 0; j < 12; j++) {
    int c = j * 256 + t;
    int r = c / 192;           // 192 float4 per x-row
    int cc = c - r * 192;      // 0..191
    int kk = cc >> 6;
    int e4 = cc & 63;
    f32x4 v = *reinterpret_cast<const f32x4*>(
        embed + (size_t)toks[r * 3 + kk] * E + e4 * 4);
    s16x4 o;
#pragma unroll
    for (int jj = 0; jj < 4; jj++) o[jj] = (short)f2bf(v[jj]);
    *reinterpret_cast<s16x4*>(&xlds[r][cc * 4]) = o;
  }
  __syncthreads();

  int l = t & 63;
  int wv = t >> 6;
  int n0 = wv * 64;

  f32x4 zero = {0.f, 0.f, 0.f, 0.f};
  f32x4 acc[4];
#pragma unroll
  for (int ni = 0; ni < 4; ni++) acc[ni] = zero;

#pragma unroll
  for (int kt = 0; kt < 24; kt++) {
    s16x8 a = *reinterpret_cast<const s16x8*>(&xlds[l & 15][kt * 32 + (l >> 4) * 8]);
#pragma unroll
    for (int ni = 0; ni < 4; ni++) {
      int n = n0 + ni * 16 + (l & 15);
      s16x8 bf = *reinterpret_cast<const s16x8*>(
          w1T + (size_t)n * K1 + kt * 32 + (l >> 4) * 8);
      acc[ni] = __builtin_amdgcn_mfma_f32_16x16x32_bf16(a, bf, acc[ni], 0, 0, 0);
    }
  }

  int rbase = m0 + (l >> 4) * 4;
#pragma unroll
  for (int ni = 0; ni < 4; ni++) {
    int n = n0 + ni * 16 + (l & 15);
    float bias = b1[n];
#pragma unroll
    for (int j = 0; j < 4; j++) {
      float vv = acc[ni][j] + bias;
      float sv = vv / (1.0f + __expf(-vv));
      hbuf[(size_t)(rbase + j) * H + n] = f2bf(sv);
    }
  }
}

// ---------------------------------------------------------------------------
// Stage 2: out = h @ w2 + b2  (8192 x 32000, K=256).
// Structure identical to round-5 (passing). ONE change: non-temporal output
// stores — the 1.05 GB write stream was churning L2/L3 every ~40 µs, forcing
// all hbuf/w2T re-fetch (1.5 GB, 20 MB working set) to HBM rates. nt-stores
// keep L3 clean so fetch runs at cache speed.
// ---------------------------------------------------------------------------
__global__ __launch_bounds__(512, 4) void k_stage2(
    const unsigned short* __restrict__ hbuf,  // (8192 x 256) bf16
    const unsigned short* __restrict__ w2T,   // (32000 x 256) bf16
    const float* __restrict__ b2, float* __restrict__ out) {
  __shared__ unsigned short lds[2][12288];  // per buf: A 256x32 (8192) + B 128x32 (4096)

  int bid = blockIdx.x;
  int rb = (bid & 7) * 1000 + (bid >> 3);  // bijective: 8000 = 8*1000
  int mtile = rb & 31;                     // 32 M-tiles of 256 (fastest)
  int ntile = rb >> 5;                     // 250 N-tiles of 128
  int m_base = mtile * 256, n_base = ntile * 128;

  int t = threadIdx.x;
  int l = t & 63;
  int wv = t >> 6;                // 0..7
  int wm = wv >> 1, wn = wv & 1;  // 4x2 wave grid; wave computes 64x64

  int srow = l >> 2;   // lane's row within a 16-row staging call (64B rows)
  int c4 = l & 3;      // lane's 16B chunk within a 64B row

  f32x4 zero = {0.f, 0.f, 0.f, 0.f};
  f32x4 acc[4][4];
#pragma unroll
  for (int mi = 0; mi < 4; mi++)
#pragma unroll
    for (int ni = 0; ni < 4; ni++) acc[mi][ni] = zero;

  // stage K-slice tt (BK=32) into buffer p: 3 gload_lds per wave.
  // Global source chunk is XOR-permuted so linear LDS dest leaves data at
  // chunk (c ^ ((row>>1)&3))  [rule 21: swizzle both sides or neither].
  auto stage = [&](int tt, int p) {
    int gk = tt * 32;
#pragma unroll
    for (int j = 0; j < 2; j++) {          // A: 256 rows
      int r0 = wv * 32 + j * 16;
      int row = r0 + srow;
      int gc = c4 ^ ((row >> 1) & 3);
      const unsigned short* ga =
          hbuf + (size_t)(m_base + row) * 256 + gk + gc * 8;
      __builtin_amdgcn_global_load_lds((gas_t)ga, (las_t)&lds[p][r0 * 32], 16, 0, 0);
    }
    {                                      // B: 128 rows
      int r0 = wv * 16;
      int row = r0 + srow;
      int gc = c4 ^ ((row >> 1) & 3);
      const unsigned short* gb =
          w2T + (size_t)(n_base + row) * 256 + gk + gc * 8;
      __builtin_amdgcn_global_load_lds((gas_t)gb, (las_t)&lds[p][8192 + r0 * 32], 16, 0, 0);
    }
  };

  auto compute = [&](int p) {
    const unsigned short* bufA = &lds[p][0];
    const unsigned short* bufB = &lds[p][8192];
    int c = l >> 4;  // lane's K-chunk (0..3)
    s16x8 af[4], bfr[4];
#pragma unroll
    for (int mi = 0; mi < 4; mi++) {
      int row = wm * 64 + mi * 16 + (l & 15);
      af[mi] = *reinterpret_cast<const s16x8*>(
          bufA + row * 32 + (c ^ ((row >> 1) & 3)) * 8);
    }
#pragma unroll
    for (int ni = 0; ni < 4; ni++) {
      int row = wn * 64 + ni * 16 + (l & 15);
      bfr[ni] = *reinterpret_cast<const s16x8*>(
          bufB + row * 32 + (c ^ ((row >> 1) & 3)) * 8);
    }
#pragma unroll
    for (int mi = 0; mi < 4; mi++)
#pragma unroll
      for (int ni = 0; ni < 4; ni++)
        acc[mi][ni] = __builtin_amdgcn_mfma_f32_16x16x32_bf16(
            af[mi], bfr[ni], acc[mi][ni], 0, 0, 0);
  };

  stage(0, 0);
  __syncthreads();
#pragma unroll
  for (int tt = 0; tt < 8; tt++) {
    if (tt < 7) stage(tt + 1, (tt + 1) & 1);  // prefetch: flies during compute
    compute(tt & 1);
    __syncthreads();  // full fence: loads landed + all reads of buf done
  }

  // epilogue: + b2, NON-TEMPORAL f32 store (don't churn L2/L3 with 1.05 GB)
#pragma unroll
  for (int ni = 0; ni < 4; ni++) {
    int col = n_base + wn * 64 + ni * 16 + (l & 15);
    float bias = b2[col];
#pragma unroll
    for (int mi = 0; mi < 4; mi++) {
      int row0 = m_base + wm * 64 + mi * 16 + ((l >> 4) * 4);
#pragma unroll
      for (int j = 0; j < 4; j++) {
        float v = acc[mi][ni][j] + bias;
        __builtin_nontemporal_store(v, &out[(size_t)(row0 + j) * V + col]);
      }
    }
  }
}

// ---------------------------------------------------------------------------
extern "C" void kernel_launch(void* const* d_in, const int* in_sizes, int n_in,
                              void* d_out, int out_size, void* d_ws,
                              size_t ws_size, hipStream_t stream) {
  const int* tokens = (const int*)d_in[0];     // (S, B)
  const float* embed = (const float*)d_in[1];  // (V, E)
  const float* w1 = (const float*)d_in[2];     // (K1, H)
  const float* b1 = (const float*)d_in[3];     // (H)
  const float* w2 = (const float*)d_in[4];     // (H, V)
  const float* b2 = (const float*)d_in[5];     // (V)
  float* out = (float*)d_out;

  unsigned short* w2T = (unsigned short*)d_ws;          // V*E   bf16
  unsigned short* w1T = w2T + (size_t)V * E;            // H*K1  bf16
  unsigned short* hb  = w1T + (size_t)H * K1;           // M*H   bf16

  k_transpose_cast<<<dim3(V / 32, H / 32), 256, 0, stream>>>(w2, w2T, H, V);
  k_transpose_cast<<<dim3(H / 32, K1 / 32), 256, 0, stream>>>(w1, w1T, K1, H);
  k_stage1<<<512, 256, 0, stream>>>(tokens, embed, w1T, b1, hb);
  k_stage2<<<8000, 512, 0, stream>>>(hb, w2T, b2, out);
}

// Round 7
// 351.093 us; speedup vs baseline: 1.4301x; 1.1672x over previous
//
#include <hip/hip_runtime.h>
#include <hip/hip_bf16.h>
#include <stdint.h>

#define V 32000
#define E 256
#define H 256
#define KCTX 3
#define S 2048
#define B 4
#define M (S * B)      // 8192 rows
#define K1 (KCTX * E)  // 768

typedef __attribute__((ext_vector_type(8))) short s16x8;
typedef __attribute__((ext_vector_type(4))) short s16x4;
typedef __attribute__((ext_vector_type(4))) float f32x4;

typedef const __attribute__((address_space(1))) unsigned short* gas_t;
typedef __attribute__((address_space(3))) unsigned short* las_t;

static __device__ __forceinline__ unsigned short f2bf(float f) {
  union { float f; unsigned u; } v; v.f = f;
  unsigned u = v.u;
  unsigned r = (u + 0x7fffu + ((u >> 16) & 1u)) >> 16;  // RNE
  return (unsigned short)r;
}

// ---------------------------------------------------------------------------
// Transpose + cast: in (R x C) f32  ->  out (C x R) bf16.  R%32==0, C%32==0.
// ---------------------------------------------------------------------------
__global__ void k_transpose_cast(const float* __restrict__ in,
                                 unsigned short* __restrict__ out,
                                 int R, int C) {
  __shared__ float tile[32][33];
  int bx = blockIdx.x;               // column-tile
  int by = blockIdx.y;               // row-tile
  int tx = threadIdx.x & 31;
  int ty = threadIdx.x >> 5;         // 0..7
#pragma unroll
  for (int i = 0; i < 32; i += 8)
    tile[ty + i][tx] = in[(size_t)(by * 32 + ty + i) * C + bx * 32 + tx];
  __syncthreads();
#pragma unroll
  for (int i = 0; i < 32; i += 8)
    out[(size_t)(bx * 32 + ty + i) * R + by * 32 + tx] = f2bf(tile[tx][ty + i]);
}

// ---------------------------------------------------------------------------
// Stage 1: h = silu(x @ w1 + b1), h bf16 (8192 x 256).
// Block = 4 waves = one 16-row M-tile; x-tile gathered once into LDS.
// ---------------------------------------------------------------------------
__global__ __launch_bounds__(256) void k_stage1(
    const int* __restrict__ tok, const float* __restrict__ embed,
    const unsigned short* __restrict__ w1T,  // (H x K1) bf16, w1T[n][k]
    const float* __restrict__ b1, unsigned short* __restrict__ hbuf) {
  __shared__ unsigned short xlds[16][K1 + 8];
  __shared__ int toks[48];
  int bid = blockIdx.x;        // 0..511
  int t = threadIdx.x;
  int m0 = bid * 16;

  if (t < 48) {
    int r = t / 3, kk = t - r * 3;
    int m = m0 + r, s = m >> 2, bb = m & 3;
    int tp = s - KCTX + kk;
    toks[t] = (tp >= 0) ? tok[tp * B + bb] : 0;
  }
  __syncthreads();

#pragma unroll
  for (int j = 0; j < 12; j++) {
    int c = j * 256 + t;
    int r = c / 192;           // 192 float4 per x-row
    int cc = c - r * 192;      // 0..191
    int kk = cc >> 6;
    int e4 = cc & 63;
    f32x4 v = *reinterpret_cast<const f32x4*>(
        embed + (size_t)toks[r * 3 + kk] * E + e4 * 4);
    s16x4 o;
#pragma unroll
    for (int jj = 0; jj < 4; jj++) o[jj] = (short)f2bf(v[jj]);
    *reinterpret_cast<s16x4*>(&xlds[r][cc * 4]) = o;
  }
  __syncthreads();

  int l = t & 63;
  int wv = t >> 6;
  int n0 = wv * 64;

  f32x4 zero = {0.f, 0.f, 0.f, 0.f};
  f32x4 acc[4];
#pragma unroll
  for (int ni = 0; ni < 4; ni++) acc[ni] = zero;

#pragma unroll
  for (int kt = 0; kt < 24; kt++) {
    s16x8 a = *reinterpret_cast<const s16x8*>(&xlds[l & 15][kt * 32 + (l >> 4) * 8]);
#pragma unroll
    for (int ni = 0; ni < 4; ni++) {
      int n = n0 + ni * 16 + (l & 15);
      s16x8 bf = *reinterpret_cast<const s16x8*>(
          w1T + (size_t)n * K1 + kt * 32 + (l >> 4) * 8);
      acc[ni] = __builtin_amdgcn_mfma_f32_16x16x32_bf16(a, bf, acc[ni], 0, 0, 0);
    }
  }

  int rbase = m0 + (l >> 4) * 4;
#pragma unroll
  for (int ni = 0; ni < 4; ni++) {
    int n = n0 + ni * 16 + (l & 15);
    float bias = b1[n];
#pragma unroll
    for (int j = 0; j < 4; j++) {
      float vv = acc[ni][j] + bias;
      float sv = vv / (1.0f + __expf(-vv));
      hbuf[(size_t)(rbase + j) * H + n] = f2bf(sv);
    }
  }
}

// ---------------------------------------------------------------------------
// Stage 2: out = h @ w2 + b2  (8192 x 32000, K=256).
// Byte-identical compute/staging to round-6 (passing, nt-stores). ONE change:
// block->tile mapping is now NTILE-FASTEST with mtiles pinned per XCD:
//   grid 8000 = 8 XCD x 4 mtiles x 250 ntiles.
// Each XCD keeps ONE 128 KB A-slice (its current mtile of hbuf) L2-resident
// for 250 consecutive blocks -> chip A-fetch drops 1.02 GB -> ~4 MB.
// B re-reads (512 MB) hit L3 (kept clean by nt output stores).
// New HBM floor ~= write 1.02 GB + ~20 MB reads ~= 155 us.
// ---------------------------------------------------------------------------
__global__ __launch_bounds__(512, 4) void k_stage2(
    const unsigned short* __restrict__ hbuf,  // (8192 x 256) bf16
    const unsigned short* __restrict__ w2T,   // (32000 x 256) bf16
    const float* __restrict__ b2, float* __restrict__ out) {
  __shared__ unsigned short lds[2][12288];  // per buf: A 256x32 (8192) + B 128x32 (4096)

  int bid = blockIdx.x;
  int xcd = bid & 7;          // dispatch round-robins XCDs
  int i = bid >> 3;           // 0..999 within XCD
  int mtile = xcd * 4 + i / 250;  // 0..31: 4 mtiles pinned per XCD
  int ntile = i % 250;            // ntile-fastest: A-slice L2-resident
  int m_base = mtile * 256, n_base = ntile * 128;

  int t = threadIdx.x;
  int l = t & 63;
  int wv = t >> 6;                // 0..7
  int wm = wv >> 1, wn = wv & 1;  // 4x2 wave grid; wave computes 64x64

  int srow = l >> 2;   // lane's row within a 16-row staging call (64B rows)
  int c4 = l & 3;      // lane's 16B chunk within a 64B row

  f32x4 zero = {0.f, 0.f, 0.f, 0.f};
  f32x4 acc[4][4];
#pragma unroll
  for (int mi = 0; mi < 4; mi++)
#pragma unroll
    for (int ni = 0; ni < 4; ni++) acc[mi][ni] = zero;

  // stage K-slice tt (BK=32) into buffer p: 3 gload_lds per wave.
  // Global source chunk is XOR-permuted so linear LDS dest leaves data at
  // chunk (c ^ ((row>>1)&3))  [rule 21: swizzle both sides or neither].
  auto stage = [&](int tt, int p) {
    int gk = tt * 32;
#pragma unroll
    for (int j = 0; j < 2; j++) {          // A: 256 rows
      int r0 = wv * 32 + j * 16;
      int row = r0 + srow;
      int gc = c4 ^ ((row >> 1) & 3);
      const unsigned short* ga =
          hbuf + (size_t)(m_base + row) * 256 + gk + gc * 8;
      __builtin_amdgcn_global_load_lds((gas_t)ga, (las_t)&lds[p][r0 * 32], 16, 0, 0);
    }
    {                                      // B: 128 rows
      int r0 = wv * 16;
      int row = r0 + srow;
      int gc = c4 ^ ((row >> 1) & 3);
      const unsigned short* gb =
          w2T + (size_t)(n_base + row) * 256 + gk + gc * 8;
      __builtin_amdgcn_global_load_lds((gas_t)gb, (las_t)&lds[p][8192 + r0 * 32], 16, 0, 0);
    }
  };

  auto compute = [&](int p) {
    const unsigned short* bufA = &lds[p][0];
    const unsigned short* bufB = &lds[p][8192];
    int c = l >> 4;  // lane's K-chunk (0..3)
    s16x8 af[4], bfr[4];
#pragma unroll
    for (int mi = 0; mi < 4; mi++) {
      int row = wm * 64 + mi * 16 + (l & 15);
      af[mi] = *reinterpret_cast<const s16x8*>(
          bufA + row * 32 + (c ^ ((row >> 1) & 3)) * 8);
    }
#pragma unroll
    for (int ni = 0; ni < 4; ni++) {
      int row = wn * 64 + ni * 16 + (l & 15);
      bfr[ni] = *reinterpret_cast<const s16x8*>(
          bufB + row * 32 + (c ^ ((row >> 1) & 3)) * 8);
    }
#pragma unroll
    for (int mi = 0; mi < 4; mi++)
#pragma unroll
      for (int ni = 0; ni < 4; ni++)
        acc[mi][ni] = __builtin_amdgcn_mfma_f32_16x16x32_bf16(
            af[mi], bfr[ni], acc[mi][ni], 0, 0, 0);
  };

  stage(0, 0);
  __syncthreads();
#pragma unroll
  for (int tt = 0; tt < 8; tt++) {
    if (tt < 7) stage(tt + 1, (tt + 1) & 1);  // prefetch: flies during compute
    compute(tt & 1);
    __syncthreads();  // full fence: loads landed + all reads of buf done
  }

  // epilogue: + b2, NON-TEMPORAL f32 store (don't churn L2/L3 with 1.05 GB)
#pragma unroll
  for (int ni = 0; ni < 4; ni++) {
    int col = n_base + wn * 64 + ni * 16 + (l & 15);
    float bias = b2[col];
#pragma unroll
    for (int mi = 0; mi < 4; mi++) {
      int row0 = m_base + wm * 64 + mi * 16 + ((l >> 4) * 4);
#pragma unroll
      for (int j = 0; j < 4; j++) {
        float v = acc[mi][ni][j] + bias;
        __builtin_nontemporal_store(v, &out[(size_t)(row0 + j) * V + col]);
      }
    }
  }
}

// ---------------------------------------------------------------------------
extern "C" void kernel_launch(void* const* d_in, const int* in_sizes, int n_in,
                              void* d_out, int out_size, void* d_ws,
                              size_t ws_size, hipStream_t stream) {
  const int* tokens = (const int*)d_in[0];     // (S, B)
  const float* embed = (const float*)d_in[1];  // (V, E)
  const float* w1 = (const float*)d_in[2];     // (K1, H)
  const float* b1 = (const float*)d_in[3];     // (H)
  const float* w2 = (const float*)d_in[4];     // (H, V)
  const float* b2 = (const float*)d_in[5];     // (V)
  float* out = (float*)d_out;

  unsigned short* w2T = (unsigned short*)d_ws;          // V*E   bf16
  unsigned short* w1T = w2T + (size_t)V * E;            // H*K1  bf16
  unsigned short* hb  = w1T + (size_t)H * K1;           // M*H   bf16

  k_transpose_cast<<<dim3(V / 32, H / 32), 256, 0, stream>>>(w2, w2T, H, V);
  k_transpose_cast<<<dim3(H / 32, K1 / 32), 256, 0, stream>>>(w1, w1T, K1, H);
  k_stage1<<<512, 256, 0, stream>>>(tokens, embed, w1T, b1, hb);
  k_stage2<<<8000, 512, 0, stream>>>(hb, w2T, b2, out);
}